// Round 5
// baseline (608.707 us; speedup 1.0000x reference)
//
#include <hip/hip_runtime.h>
#include <stdint.h>

#define EPSF 1e-7f
#define MAXTAN 10.0f

typedef __bf16 bf16x8 __attribute__((ext_vector_type(8)));
typedef float floatx4 __attribute__((ext_vector_type(4)));
typedef __attribute__((address_space(3))) void lds_void_t;
typedef __attribute__((address_space(1))) void gbl_void_t;

__device__ __forceinline__ unsigned short f2bf(float x) {
  union { float f; uint32_t u; } v; v.f = x;
  uint32_t u = v.u;
  u += 0x7fffu + ((u >> 16) & 1u);   // RNE
  return (unsigned short)(u >> 16);
}
__device__ __forceinline__ float bf2f(unsigned short h) {
  union { uint32_t u; float f; } v; v.u = ((uint32_t)h) << 16;
  return v.f;
}

__device__ __forceinline__ int sniff_mode(const unsigned short* x) {
  int sane = 0;
  for (int i = 0; i < 128; ++i) {
    unsigned short h = x[i];
    int e = (h >> 7) & 0xFF;
    if ((h & 0x7FFF) == 0 || (e >= 96 && e <= 140)) ++sane;
  }
  return (sane >= 120) ? 1 : 0;
}

// ---------------- init: sniff dtype + convert biases ----------------
__global__ void k_init(const unsigned short* __restrict__ x, int* __restrict__ modeg,
                       const void* __restrict__ b1, const void* __restrict__ b2,
                       const void* __restrict__ b3, float* __restrict__ o1,
                       float* __restrict__ o2, float* __restrict__ o3) {
  __shared__ int mds;
  if (threadIdx.x == 0) {
    int m = sniff_mode(x);
    mds = m;
    if (blockIdx.x == 0) *modeg = m;
  }
  __syncthreads();
  int m = mds;
  int i = blockIdx.x * 256 + threadIdx.x;
  if (i < 4096) o1[i] = m ? bf2f(((const unsigned short*)b1)[i]) : ((const float*)b1)[i];
  if (i < 4096) o2[i] = m ? bf2f(((const unsigned short*)b2)[i]) : ((const float*)b2)[i];
  if (i < 1024) o3[i] = m ? bf2f(((const unsigned short*)b3)[i]) : ((const float*)b3)[i];
}

// ---------------- x prep: convert to bf16, compute logmap scale + x0 ----------------
__global__ void k_prep(const void* __restrict__ xv, unsigned short* __restrict__ xb,
                       float* __restrict__ sc0, float* __restrict__ x0c,
                       const int* __restrict__ mode) {
  const int row = blockIdx.x;
  const int tid = threadIdx.x;
  float4 v;
  if (*mode) {
    ushort4 u = ((const ushort4*)((const unsigned short*)xv + (size_t)row * 1024))[tid];
    v.x = bf2f(u.x); v.y = bf2f(u.y); v.z = bf2f(u.z); v.w = bf2f(u.w);
  } else {
    v = ((const float4*)((const float*)xv + (size_t)row * 1024))[tid];
  }
  ushort4 o;
  o.x = f2bf(v.x); o.y = f2bf(v.y); o.z = f2bf(v.z); o.w = f2bf(v.w);
  ((ushort4*)(xb + (size_t)row * 1024))[tid] = o;

  float s = v.x * v.x + v.y * v.y + v.z * v.z + v.w * v.w;
  if (tid == 0) s -= v.x * v.x;          // exclude time coordinate
  for (int off = 32; off; off >>= 1) s += __shfl_down(s, off, 64);
  __shared__ float red[4];
  if ((tid & 63) == 0) red[tid >> 6] = s;
  __syncthreads();
  if (tid == 0) {
    s = red[0] + red[1] + red[2] + red[3];
    float ns = fmaxf(sqrtf(s), EPSF);
    float d = acoshf(fmaxf(v.x, 1.0f + EPSF));
    sc0[row] = d / ns;
    x0c[row] = bf2f(o.x);
  }
}

// ---------------- weight convert to bf16 + col0 extraction ----------------
template<int K8>
__global__ void k_cvtw(const void* __restrict__ in, unsigned short* __restrict__ out,
                       const int* __restrict__ mode, int n8, float* __restrict__ c0) {
  int i = blockIdx.x * 256 + threadIdx.x;
  if (i >= n8) return;
  if (*mode) {
    uint4 g = ((const uint4*)in)[i];
    ((uint4*)out)[i] = g;
    if (i % K8 == 0) c0[i / K8] = bf2f((unsigned short)(g.x & 0xFFFFu));
  } else {
    float4 a = ((const float4*)in)[2 * i];
    float4 b = ((const float4*)in)[2 * i + 1];
    ushort4 oa, ob;
    oa.x = f2bf(a.x); oa.y = f2bf(a.y); oa.z = f2bf(a.z); oa.w = f2bf(a.w);
    ob.x = f2bf(b.x); ob.y = f2bf(b.y); ob.z = f2bf(b.z); ob.w = f2bf(b.w);
    ((ushort4*)out)[2 * i] = oa;
    ((ushort4*)out)[2 * i + 1] = ob;
    if (i % K8 == 0) c0[i / K8] = bf2f(oa.x);
  }
}

// ---------------- partial-sumsq fold -> scale + col0 grab ----------------
template<int NBLK>
__global__ void k_sc(const float* __restrict__ part, const unsigned short* __restrict__ y,
                     int stride, float* __restrict__ sc, float* __restrict__ c0,
                     float* __restrict__ ssout, int nrows) {
  int i = blockIdx.x * 256 + threadIdx.x;
  if (i >= nrows) return;
  float s = 0.f;
#pragma unroll
  for (int j = 0; j < NBLK; ++j) s += part[(size_t)i * NBLK + j];
  float n = fmaxf(sqrtf(fmaxf(s, 0.f)), EPSF);
  sc[i] = fminf(n, MAXTAN) / n;
  c0[i] = bf2f(y[(size_t)i * stride]);
  if (ssout) ssout[i] = s;
}

// ---------------- final: y3 bf16 + ss3 -> projx(safe_expmap0(y3)) ----------------
__global__ void k_final(const unsigned short* __restrict__ y, const float* __restrict__ ss,
                        void* __restrict__ outv, const int* __restrict__ mode) {
  const int row = blockIdx.x;
  const int tid = threadIdx.x;
  float n = fmaxf(sqrtf(fmaxf(ss[row], 0.f)), EPSF);
  float nc = fminf(n, MAXTAN);
  float a = sinhf(nc) / n;
  ushort4 u = ((const ushort4*)(y + (size_t)row * 1024))[tid];
  float4 o;
  o.x = bf2f(u.x) * a; o.y = bf2f(u.y) * a;
  o.z = bf2f(u.z) * a; o.w = bf2f(u.w) * a;
  if (tid == 0) o.x = coshf(nc);
  if (*mode) {
    ushort4 o16;
    o16.x = f2bf(o.x); o16.y = f2bf(o.y); o16.z = f2bf(o.z); o16.w = f2bf(o.w);
    ((ushort4*)outv)[(size_t)row * 256 + tid] = o16;
  } else {
    ((float4*)outv)[(size_t)row * 256 + tid] = o;
  }
}

// ---------------- legacy 128x128 NT GEMM (kept for GEMM3: N=1024 grid too small for 256^2) ----------------
template<int N, int K, int NBLK, int GX>
__global__ __launch_bounds__(256, 4) void k_gemm_bt(
    const unsigned short* __restrict__ A,
    const unsigned short* __restrict__ B,
    const float* __restrict__ bias,
    const float* __restrict__ sc,
    const float* __restrict__ c0f,
    const float* __restrict__ wc0,
    unsigned short* __restrict__ Cb,
    float* __restrict__ part)
{
  __shared__ __align__(16) unsigned short As[128 * 32];
  __shared__ __align__(16) unsigned short Bs[128 * 32];

  const int tid  = threadIdx.x;
  const int wave = tid >> 6;
  const int lane = tid & 63;
  const int quad = lane >> 4;
  const int m16  = lane & 15;

  const int j = blockIdx.x & 7;
  const int k = blockIdx.x >> 3;
  int bxi, byi;
  if (GX == 32) {
    bxi = 16 * (j & 1) + (k & 15);
    byi = 16 * (j >> 1) + (k >> 4);
  } else {
    bxi = k & 7;
    byi = 8 * j + (k >> 3);
  }
  const int bm = byi * 128;
  const int bn = bxi * 128;

  const int srow = lane >> 2;
  const int scol = (((lane & 3) ^ ((srow >> 1) & 3)) << 3);

  const int wm = (wave >> 1) << 6;
  const int wn = (wave & 1) << 6;

  const int rsw = ((quad ^ ((m16 >> 1) & 3)) << 3);

  const int c0i = wave * 2;
  const unsigned short* ga0 = A + (size_t)(bm + c0i * 16 + srow) * K + scol;
  const unsigned short* ga1 = ga0 + (size_t)16 * K;
  const unsigned short* gb0 = B + (size_t)(bn + c0i * 16 + srow) * K + scol;
  const unsigned short* gb1 = gb0 + (size_t)16 * K;

  floatx4 acc[4][4];
#pragma unroll
  for (int i = 0; i < 4; ++i)
#pragma unroll
    for (int jj = 0; jj < 4; ++jj)
#pragma unroll
      for (int r = 0; r < 4; ++r) acc[i][jj][r] = 0.0f;

  for (int k0 = 0; k0 < K; k0 += 32) {
    __builtin_amdgcn_global_load_lds((gbl_void_t*)(void*)ga0,
                                     (lds_void_t*)(As + c0i * 512), 16, 0, 0);
    __builtin_amdgcn_global_load_lds((gbl_void_t*)(void*)ga1,
                                     (lds_void_t*)(As + c0i * 512 + 512), 16, 0, 0);
    __builtin_amdgcn_global_load_lds((gbl_void_t*)(void*)gb0,
                                     (lds_void_t*)(Bs + c0i * 512), 16, 0, 0);
    __builtin_amdgcn_global_load_lds((gbl_void_t*)(void*)gb1,
                                     (lds_void_t*)(Bs + c0i * 512 + 512), 16, 0, 0);
    ga0 += 32; ga1 += 32; gb0 += 32; gb1 += 32;
    __syncthreads();

    bf16x8 af[4], bfg[4];
#pragma unroll
    for (int t = 0; t < 4; ++t) {
      af[t]  = *(const bf16x8*)(As + (wm + t * 16 + m16) * 32 + rsw);
      bfg[t] = *(const bf16x8*)(Bs + (wn + t * 16 + m16) * 32 + rsw);
    }
#pragma unroll
    for (int mt = 0; mt < 4; ++mt)
#pragma unroll
      for (int nt = 0; nt < 4; ++nt)
        acc[mt][nt] = __builtin_amdgcn_mfma_f32_16x16x32_bf16(af[mt], bfg[nt], acc[mt][nt], 0, 0, 0);
    __syncthreads();
  }

#pragma unroll
  for (int mt = 0; mt < 4; ++mt) {
#pragma unroll
    for (int r = 0; r < 4; ++r) {
      const int gm = bm + wm + mt * 16 + quad * 4 + r;
      const float scv = sc[gm];
      const float c0v = c0f[gm];
      float sq = 0.f;
#pragma unroll
      for (int nt = 0; nt < 4; ++nt) {
        const int gn = bn + wn + nt * 16 + m16;
        float v = scv * (acc[mt][nt][r] - c0v * wc0[gn]) + bias[gn];
        Cb[(size_t)gm * N + gn] = f2bf(v);
        sq += (gn == 0) ? 0.f : v * v;
      }
      sq += __shfl_xor(sq, 1, 64);
      sq += __shfl_xor(sq, 2, 64);
      sq += __shfl_xor(sq, 4, 64);
      sq += __shfl_xor(sq, 8, 64);
      if (m16 == 0) part[(size_t)gm * NBLK + 2 * bxi + (wave & 1)] = sq;
    }
  }
}

// ---------------- 256x256 NT GEMM, fragment-read-ahead pipeline ----------------
// 512 threads = 8 waves (2M x 4N); per-wave 128x64 output, acc[8][4].
// LDS: 4-slot ring of (A 256x32 + B 256x32) bf16 = 4 x 32KB = 128KB.
// R5 model (validated by R3/R4 nulls + cycle accounting): iter = 2404 cyc =
//   MFMA 1242 + LDS 1152 back-to-back -- each wave's 12 ds_reads feed ITS OWN
//   32 MFMAs, so the lgkmcnt wait serializes read-burst -> MFMA-burst.
// R5 change: REGISTER DOUBLE-BUFFER of a/b fragments one iteration ahead.
//   Iter t: {GLL(t+3); read a2(t) [4]; MFMA phase A with a(t),b(t) (read in t-1);
//            read a(t+1),b(t+1) [8]; MFMA phase B with a2(t),b(t); vmcnt(4); barrier}.
//   No MFMA waits on a read issued in its own iteration; the 12-read burst drains
//   under the 1242-cyc MFMA stretch. New floor ~= LDS pipe: 1152+256 GLL-writes.
// vmcnt DEEPENED 8->4: reading frags(t+1) during iter t requires tile t+1 resident
//   at iter-t start; end-of-(t-1) vmcnt(4) leaves only tile t+2's 4 loads in flight.
//   Prologue: 12 loads then vmcnt(4) -> tiles 0,1 resident (frags(0) + frags(1) ok).
// WAR audit: GLL(t) writes slot (t+3)&3=(t-1)&3; reads of that slot (issued t-2,
//   used t-1 phase A) are lgkm-consumed before the end-of-(t-1) barrier ✓.
//   In-flight reads at GLL issue target slots t&3 and (t+1)&3 only ✓.
// Loop unrolled x2 alternating named register sets (static indexing, rule #20).
// Granule swizzle (measured 0 conflicts): LDS granule g of row r = global g ^ ((r>>1)&3).
// Epilogue: y = sc[m]*(acc - c0f[m]*wc0[n]) + bias[n]; partials part[gm*64 + bxi*4 + wc].
template<int N, int K>
__global__ __launch_bounds__(512, 2) void k_gemm256(
    const unsigned short* __restrict__ A,
    const unsigned short* __restrict__ B,
    const float* __restrict__ bias,
    const float* __restrict__ sc,
    const float* __restrict__ c0f,
    const float* __restrict__ wc0,
    unsigned short* __restrict__ Cb,
    float* __restrict__ part)
{
  static_assert(K % 64 == 0 && K / 32 >= 4, "need even NT >= 4");
  constexpr int NT = K / 32;
  __shared__ __align__(16) unsigned short S[4][2][8192];   // [slot][A/B][256*32]

  const int tid  = threadIdx.x;
  const int wave = tid >> 6;
  const int lane = tid & 63;
  const int quad = lane >> 4;
  const int m16  = lane & 15;
  const int wr   = wave >> 2;     // 0..1 (M)
  const int wc   = wave & 3;      // 0..3 (N)

  // bijective XCD swizzle: 512 blocks = 8 XCDs x 64; each XCD gets an 8x8 tile patch
  const int j = blockIdx.x & 7;
  const int k = blockIdx.x >> 3;                 // 0..63
  const int bxi = 8 * (j & 1) + (k & 7);         // 0..15  (N/256)
  const int byi = 8 * (j >> 1) + (k >> 3);       // 0..31  (M/256)
  const int bm = byi * 256;
  const int bn = bxi * 256;

  // staging: thread -> row tid>>2 (0..127), LDS granule tid&3; global granule pre-swizzled
  const int gsw8 = (((tid & 3) ^ ((tid >> 3) & 3)) << 3);
  const unsigned short* gA = A + (size_t)(bm + (tid >> 2)) * K + gsw8;
  const unsigned short* gB = B + (size_t)(bn + (tid >> 2)) * K + gsw8;
  const int ld0 = wave * 512;          // rows  wave*16 .. +15
  const int ld1 = 4096 + wave * 512;   // rows 128+wave*16 .. +15

  // read-side swizzle + fragment base offsets (elements)
  const int rsw8 = ((quad ^ ((m16 >> 1) & 3)) << 3);
  const int aoff = (wr * 128 + m16) * 32 + rsw8;
  const int boff = (wc * 64  + m16) * 32 + rsw8;

  floatx4 acc[8][4];
#pragma unroll
  for (int i = 0; i < 8; ++i)
#pragma unroll
    for (int jj = 0; jj < 4; ++jj)
#pragma unroll
      for (int r = 0; r < 4; ++r) acc[i][jj][r] = 0.0f;

#define GLL(SRC, DST) __builtin_amdgcn_global_load_lds((gbl_void_t*)(void*)(SRC), (lds_void_t*)(DST), 16, 0, 0)

  // prologue: stage tiles 0,1,2 (12 loads/thread); vmcnt(4) -> tiles 0,1 resident
#pragma unroll
  for (int tt = 0; tt < 3; ++tt) {
    const unsigned short* pa = gA + tt * 32;
    const unsigned short* pb = gB + tt * 32;
    GLL(pa,                   &S[tt][0][ld0]);
    GLL(pa + (size_t)128 * K, &S[tt][0][ld1]);
    GLL(pb,                   &S[tt][1][ld0]);
    GLL(pb + (size_t)128 * K, &S[tt][1][ld1]);
  }
  asm volatile("s_waitcnt vmcnt(4)" ::: "memory");
  __builtin_amdgcn_s_barrier();

  // pre-read frags of tile 0 into set X
  bf16x8 aX[4], bX[4], aY[4], bY[4];
#pragma unroll
  for (int f = 0; f < 4; ++f) aX[f] = *(const bf16x8*)(&S[0][0][0] + aoff + f * 512);
#pragma unroll
  for (int n = 0; n < 4; ++n) bX[n] = *(const bf16x8*)(&S[0][1][0] + boff + n * 512);

  // one pipelined iteration: compute tile T from AC/BC, read tile T+1 into AN/BN
#define ITER(T, AC, BC, AN, BN)                                                        \
  {                                                                                    \
    const int slot_ = (T) & 3;                                                         \
    const int s3_   = ((T) + 3) & 3;                                                   \
    const int kt_   = ((T) + 3 < NT ? (T) + 3 : NT - 1) * 32;                          \
    GLL(gA + kt_,                   &S[s3_][0][ld0]);                                  \
    GLL(gA + kt_ + (size_t)128 * K, &S[s3_][0][ld1]);                                  \
    GLL(gB + kt_,                   &S[s3_][1][ld0]);                                  \
    GLL(gB + kt_ + (size_t)128 * K, &S[s3_][1][ld1]);                                  \
    bf16x8 a2_[4];                                                                     \
    _Pragma("unroll")                                                                  \
    for (int f = 0; f < 4; ++f)                                                        \
      a2_[f] = *(const bf16x8*)(&S[slot_][0][0] + aoff + 2048 + f * 512);              \
    __builtin_amdgcn_s_setprio(1);                                                     \
    _Pragma("unroll")                                                                  \
    for (int f = 0; f < 4; ++f)                                                        \
      _Pragma("unroll")                                                                \
      for (int n = 0; n < 4; ++n)                                                      \
        acc[f][n] = __builtin_amdgcn_mfma_f32_16x16x32_bf16(AC[f], BC[n], acc[f][n], 0, 0, 0); \
    __builtin_amdgcn_s_setprio(0);                                                     \
    const int sn_ = ((T) + 1 < NT ? (T) + 1 : NT - 1) & 3;                             \
    _Pragma("unroll")                                                                  \
    for (int f = 0; f < 4; ++f)                                                        \
      AN[f] = *(const bf16x8*)(&S[sn_][0][0] + aoff + f * 512);                        \
    _Pragma("unroll")                                                                  \
    for (int n = 0; n < 4; ++n)                                                        \
      BN[n] = *(const bf16x8*)(&S[sn_][1][0] + boff + n * 512);                        \
    __builtin_amdgcn_s_setprio(1);                                                     \
    _Pragma("unroll")                                                                  \
    for (int f = 0; f < 4; ++f)                                                        \
      _Pragma("unroll")                                                                \
      for (int n = 0; n < 4; ++n)                                                      \
        acc[f + 4][n] = __builtin_amdgcn_mfma_f32_16x16x32_bf16(a2_[f], BC[n], acc[f + 4][n], 0, 0, 0); \
    __builtin_amdgcn_s_setprio(0);                                                     \
    asm volatile("s_waitcnt vmcnt(4)" ::: "memory");                                   \
    __builtin_amdgcn_s_barrier();                                                      \
  }

  for (int t = 0; t < NT; t += 2) {
    ITER(t,     aX, bX, aY, bY)
    ITER(t + 1, aY, bY, aX, bX)
  }
#undef ITER
#undef GLL

  // drain outstanding global_load_lds before waves can retire (LDS is freed at endpgm)
  asm volatile("s_waitcnt vmcnt(0)" ::: "memory");

  // epilogue: C/D layout col = lane&15, row = quad*4 + r
  const int wm = wr * 128;
  const int wn = wc * 64;
#pragma unroll
  for (int mt = 0; mt < 8; ++mt) {
#pragma unroll
    for (int r = 0; r < 4; ++r) {
      const int gm = bm + wm + mt * 16 + quad * 4 + r;
      const float scv = sc[gm];
      const float c0v = c0f[gm];
      float sq = 0.f;
#pragma unroll
      for (int nt = 0; nt < 4; ++nt) {
        const int gn = bn + wn + nt * 16 + m16;
        float v = scv * (acc[mt][nt][r] - c0v * wc0[gn]) + bias[gn];
        Cb[(size_t)gm * N + gn] = f2bf(v);
        sq += (gn == 0) ? 0.f : v * v;
      }
      sq += __shfl_xor(sq, 1, 64);
      sq += __shfl_xor(sq, 2, 64);
      sq += __shfl_xor(sq, 4, 64);
      sq += __shfl_xor(sq, 8, 64);
      if (m16 == 0) part[(size_t)gm * 64 + bxi * 4 + wc] = sq;
    }
  }
}

extern "C" void kernel_launch(void* const* d_in, const int* in_sizes, int n_in,
                              void* d_out, int out_size, void* d_ws, size_t ws_size,
                              hipStream_t stream) {
  const void* x  = d_in[0];
  const void* W1 = d_in[1];
  const void* b1 = d_in[2];
  const void* W2 = d_in[3];
  const void* b2 = d_in[4];
  const void* W3 = d_in[5];
  const void* b3 = d_in[6];

  const int NR = 8192, DIN = 1024, DH = 4096, DOUT = 1024;

  char* ws = (char*)d_ws;
  size_t off = 0;
  int* mode = (int*)(ws + off);                        off += 256;
  unsigned short* W1b = (unsigned short*)(ws + off);   off += (size_t)DH * DIN * 2;
  unsigned short* W2b = (unsigned short*)(ws + off);   off += (size_t)DH * DH * 2;
  unsigned short* W3b = (unsigned short*)(ws + off);   off += (size_t)DOUT * DH * 2;
  unsigned short* xb  = (unsigned short*)(ws + off);   off += (size_t)NR * DIN * 2;
  unsigned short* y1  = (unsigned short*)(ws + off);   off += (size_t)NR * DH * 2;
  unsigned short* y2  = (unsigned short*)(ws + off);   off += (size_t)NR * DH * 2;
  unsigned short* y3  = (unsigned short*)(ws + off);   off += (size_t)NR * DOUT * 2;
  float* part1 = (float*)(ws + off);                   off += (size_t)NR * 64 * 4;
  float* part2 = (float*)(ws + off);                   off += (size_t)NR * 64 * 4;
  float* part3 = (float*)(ws + off);                   off += (size_t)NR * 16 * 4;
  float* sc0  = (float*)(ws + off);                    off += (size_t)NR * 4;
  float* x0c  = (float*)(ws + off);                    off += (size_t)NR * 4;
  float* sc1  = (float*)(ws + off);                    off += (size_t)NR * 4;
  float* c01  = (float*)(ws + off);                    off += (size_t)NR * 4;
  float* sc2  = (float*)(ws + off);                    off += (size_t)NR * 4;
  float* c02  = (float*)(ws + off);                    off += (size_t)NR * 4;
  float* ss3  = (float*)(ws + off);                    off += (size_t)NR * 4;
  float* w1c0 = (float*)(ws + off);                    off += (size_t)DH * 4;
  float* w2c0 = (float*)(ws + off);                    off += (size_t)DH * 4;
  float* w3c0 = (float*)(ws + off);                    off += (size_t)DOUT * 4;
  float* b1f  = (float*)(ws + off);                    off += (size_t)DH * 4;
  float* b2f  = (float*)(ws + off);                    off += (size_t)DH * 4;
  float* b3f  = (float*)(ws + off);                    off += (size_t)DOUT * 4;

  k_init<<<16, 256, 0, stream>>>((const unsigned short*)x, mode, b1, b2, b3, b1f, b2f, b3f);

  k_cvtw<128><<<(DH * DIN / 8 + 255) / 256, 256, 0, stream>>>(W1, W1b, mode, DH * DIN / 8, w1c0);
  k_cvtw<512><<<(DH * DH  / 8 + 255) / 256, 256, 0, stream>>>(W2, W2b, mode, DH * DH / 8, w2c0);
  k_cvtw<512><<<(DOUT * DH / 8 + 255) / 256, 256, 0, stream>>>(W3, W3b, mode, DOUT * DH / 8, w3c0);

  k_prep<<<NR, 256, 0, stream>>>(x, xb, sc0, x0c, mode);

  k_gemm256<4096, 1024><<<512, 512, 0, stream>>>(
      xb, W1b, b1f, sc0, x0c, w1c0, y1, part1);
  k_sc<64><<<(NR + 255) / 256, 256, 0, stream>>>(part1, y1, DH, sc1, c01, nullptr, NR);

  k_gemm256<4096, 4096><<<512, 512, 0, stream>>>(
      y1, W2b, b2f, sc1, c01, w2c0, y2, part2);
  k_sc<64><<<(NR + 255) / 256, 256, 0, stream>>>(part2, y2, DH, sc2, c02, nullptr, NR);

  k_gemm_bt<1024, 4096, 16, 8><<<512, 256, 0, stream>>>(
      y2, W3b, b3f, sc2, c02, w3c0, y3, part3);
  k_sc<16><<<(NR + 255) / 256, 256, 0, stream>>>(part3, y3, DOUT, sc0, x0c, ss3, NR);

  k_final<<<NR, 256, 0, stream>>>(y3, ss3, d_out, mode);
}

// Round 6
// 594.145 us; speedup vs baseline: 1.0245x; 1.0245x over previous
//
#include <hip/hip_runtime.h>
#include <stdint.h>

#define EPSF 1e-7f
#define MAXTAN 10.0f

typedef __bf16 bf16x8 __attribute__((ext_vector_type(8)));
typedef float floatx4 __attribute__((ext_vector_type(4)));
typedef __attribute__((address_space(3))) void lds_void_t;
typedef __attribute__((address_space(1))) void gbl_void_t;

__device__ __forceinline__ unsigned short f2bf(float x) {
  union { float f; uint32_t u; } v; v.f = x;
  uint32_t u = v.u;
  u += 0x7fffu + ((u >> 16) & 1u);   // RNE
  return (unsigned short)(u >> 16);
}
__device__ __forceinline__ float bf2f(unsigned short h) {
  union { uint32_t u; float f; } v; v.u = ((uint32_t)h) << 16;
  return v.f;
}

__device__ __forceinline__ int sniff_mode(const unsigned short* x) {
  int sane = 0;
  for (int i = 0; i < 128; ++i) {
    unsigned short h = x[i];
    int e = (h >> 7) & 0xFF;
    if ((h & 0x7FFF) == 0 || (e >= 96 && e <= 140)) ++sane;
  }
  return (sane >= 120) ? 1 : 0;
}

// ---------------- init: sniff dtype + convert biases ----------------
__global__ void k_init(const unsigned short* __restrict__ x, int* __restrict__ modeg,
                       const void* __restrict__ b1, const void* __restrict__ b2,
                       const void* __restrict__ b3, float* __restrict__ o1,
                       float* __restrict__ o2, float* __restrict__ o3) {
  __shared__ int mds;
  if (threadIdx.x == 0) {
    int m = sniff_mode(x);
    mds = m;
    if (blockIdx.x == 0) *modeg = m;
  }
  __syncthreads();
  int m = mds;
  int i = blockIdx.x * 256 + threadIdx.x;
  if (i < 4096) o1[i] = m ? bf2f(((const unsigned short*)b1)[i]) : ((const float*)b1)[i];
  if (i < 4096) o2[i] = m ? bf2f(((const unsigned short*)b2)[i]) : ((const float*)b2)[i];
  if (i < 1024) o3[i] = m ? bf2f(((const unsigned short*)b3)[i]) : ((const float*)b3)[i];
}

// ---------------- x prep: convert to bf16, compute logmap scale + x0 ----------------
__global__ void k_prep(const void* __restrict__ xv, unsigned short* __restrict__ xb,
                       float* __restrict__ sc0, float* __restrict__ x0c,
                       const int* __restrict__ mode) {
  const int row = blockIdx.x;
  const int tid = threadIdx.x;
  float4 v;
  if (*mode) {
    ushort4 u = ((const ushort4*)((const unsigned short*)xv + (size_t)row * 1024))[tid];
    v.x = bf2f(u.x); v.y = bf2f(u.y); v.z = bf2f(u.z); v.w = bf2f(u.w);
  } else {
    v = ((const float4*)((const float*)xv + (size_t)row * 1024))[tid];
  }
  ushort4 o;
  o.x = f2bf(v.x); o.y = f2bf(v.y); o.z = f2bf(v.z); o.w = f2bf(v.w);
  ((ushort4*)(xb + (size_t)row * 1024))[tid] = o;

  float s = v.x * v.x + v.y * v.y + v.z * v.z + v.w * v.w;
  if (tid == 0) s -= v.x * v.x;          // exclude time coordinate
  for (int off = 32; off; off >>= 1) s += __shfl_down(s, off, 64);
  __shared__ float red[4];
  if ((tid & 63) == 0) red[tid >> 6] = s;
  __syncthreads();
  if (tid == 0) {
    s = red[0] + red[1] + red[2] + red[3];
    float ns = fmaxf(sqrtf(s), EPSF);
    float d = acoshf(fmaxf(v.x, 1.0f + EPSF));
    sc0[row] = d / ns;
    x0c[row] = bf2f(o.x);
  }
}

// ---------------- weight convert to bf16 + col0 extraction ----------------
template<int K8>
__global__ void k_cvtw(const void* __restrict__ in, unsigned short* __restrict__ out,
                       const int* __restrict__ mode, int n8, float* __restrict__ c0) {
  int i = blockIdx.x * 256 + threadIdx.x;
  if (i >= n8) return;
  if (*mode) {
    uint4 g = ((const uint4*)in)[i];
    ((uint4*)out)[i] = g;
    if (i % K8 == 0) c0[i / K8] = bf2f((unsigned short)(g.x & 0xFFFFu));
  } else {
    float4 a = ((const float4*)in)[2 * i];
    float4 b = ((const float4*)in)[2 * i + 1];
    ushort4 oa, ob;
    oa.x = f2bf(a.x); oa.y = f2bf(a.y); oa.z = f2bf(a.z); oa.w = f2bf(a.w);
    ob.x = f2bf(b.x); ob.y = f2bf(b.y); ob.z = f2bf(b.z); ob.w = f2bf(b.w);
    ((ushort4*)out)[2 * i] = oa;
    ((ushort4*)out)[2 * i + 1] = ob;
    if (i % K8 == 0) c0[i / K8] = bf2f(oa.x);
  }
}

// ---------------- partial-sumsq fold -> scale + col0 grab ----------------
template<int NBLK>
__global__ void k_sc(const float* __restrict__ part, const unsigned short* __restrict__ y,
                     int stride, float* __restrict__ sc, float* __restrict__ c0,
                     float* __restrict__ ssout, int nrows) {
  int i = blockIdx.x * 256 + threadIdx.x;
  if (i >= nrows) return;
  float s = 0.f;
#pragma unroll
  for (int j = 0; j < NBLK; ++j) s += part[(size_t)i * NBLK + j];
  float n = fmaxf(sqrtf(fmaxf(s, 0.f)), EPSF);
  sc[i] = fminf(n, MAXTAN) / n;
  c0[i] = bf2f(y[(size_t)i * stride]);
  if (ssout) ssout[i] = s;
}

// ---------------- final: y3 bf16 + ss3 -> projx(safe_expmap0(y3)) ----------------
__global__ void k_final(const unsigned short* __restrict__ y, const float* __restrict__ ss,
                        void* __restrict__ outv, const int* __restrict__ mode) {
  const int row = blockIdx.x;
  const int tid = threadIdx.x;
  float n = fmaxf(sqrtf(fmaxf(ss[row], 0.f)), EPSF);
  float nc = fminf(n, MAXTAN);
  float a = sinhf(nc) / n;
  ushort4 u = ((const ushort4*)(y + (size_t)row * 1024))[tid];
  float4 o;
  o.x = bf2f(u.x) * a; o.y = bf2f(u.y) * a;
  o.z = bf2f(u.z) * a; o.w = bf2f(u.w) * a;
  if (tid == 0) o.x = coshf(nc);
  if (*mode) {
    ushort4 o16;
    o16.x = f2bf(o.x); o16.y = f2bf(o.y); o16.z = f2bf(o.z); o16.w = f2bf(o.w);
    ((ushort4*)outv)[(size_t)row * 256 + tid] = o16;
  } else {
    ((float4*)outv)[(size_t)row * 256 + tid] = o;
  }
}

// ---------------- legacy 128x128 NT GEMM (kept for GEMM3: N=1024 grid too small for 256^2) ----------------
template<int N, int K, int NBLK, int GX>
__global__ __launch_bounds__(256, 4) void k_gemm_bt(
    const unsigned short* __restrict__ A,
    const unsigned short* __restrict__ B,
    const float* __restrict__ bias,
    const float* __restrict__ sc,
    const float* __restrict__ c0f,
    const float* __restrict__ wc0,
    unsigned short* __restrict__ Cb,
    float* __restrict__ part)
{
  __shared__ __align__(16) unsigned short As[128 * 32];
  __shared__ __align__(16) unsigned short Bs[128 * 32];

  const int tid  = threadIdx.x;
  const int wave = tid >> 6;
  const int lane = tid & 63;
  const int quad = lane >> 4;
  const int m16  = lane & 15;

  const int j = blockIdx.x & 7;
  const int k = blockIdx.x >> 3;
  int bxi, byi;
  if (GX == 32) {
    bxi = 16 * (j & 1) + (k & 15);
    byi = 16 * (j >> 1) + (k >> 4);
  } else {
    bxi = k & 7;
    byi = 8 * j + (k >> 3);
  }
  const int bm = byi * 128;
  const int bn = bxi * 128;

  const int srow = lane >> 2;
  const int scol = (((lane & 3) ^ ((srow >> 1) & 3)) << 3);

  const int wm = (wave >> 1) << 6;
  const int wn = (wave & 1) << 6;

  const int rsw = ((quad ^ ((m16 >> 1) & 3)) << 3);

  const int c0i = wave * 2;
  const unsigned short* ga0 = A + (size_t)(bm + c0i * 16 + srow) * K + scol;
  const unsigned short* ga1 = ga0 + (size_t)16 * K;
  const unsigned short* gb0 = B + (size_t)(bn + c0i * 16 + srow) * K + scol;
  const unsigned short* gb1 = gb0 + (size_t)16 * K;

  floatx4 acc[4][4];
#pragma unroll
  for (int i = 0; i < 4; ++i)
#pragma unroll
    for (int jj = 0; jj < 4; ++jj)
#pragma unroll
      for (int r = 0; r < 4; ++r) acc[i][jj][r] = 0.0f;

  for (int k0 = 0; k0 < K; k0 += 32) {
    __builtin_amdgcn_global_load_lds((gbl_void_t*)(void*)ga0,
                                     (lds_void_t*)(As + c0i * 512), 16, 0, 0);
    __builtin_amdgcn_global_load_lds((gbl_void_t*)(void*)ga1,
                                     (lds_void_t*)(As + c0i * 512 + 512), 16, 0, 0);
    __builtin_amdgcn_global_load_lds((gbl_void_t*)(void*)gb0,
                                     (lds_void_t*)(Bs + c0i * 512), 16, 0, 0);
    __builtin_amdgcn_global_load_lds((gbl_void_t*)(void*)gb1,
                                     (lds_void_t*)(Bs + c0i * 512 + 512), 16, 0, 0);
    ga0 += 32; ga1 += 32; gb0 += 32; gb1 += 32;
    __syncthreads();

    bf16x8 af[4], bfg[4];
#pragma unroll
    for (int t = 0; t < 4; ++t) {
      af[t]  = *(const bf16x8*)(As + (wm + t * 16 + m16) * 32 + rsw);
      bfg[t] = *(const bf16x8*)(Bs + (wn + t * 16 + m16) * 32 + rsw);
    }
#pragma unroll
    for (int mt = 0; mt < 4; ++mt)
#pragma unroll
      for (int nt = 0; nt < 4; ++nt)
        acc[mt][nt] = __builtin_amdgcn_mfma_f32_16x16x32_bf16(af[mt], bfg[nt], acc[mt][nt], 0, 0, 0);
    __syncthreads();
  }

#pragma unroll
  for (int mt = 0; mt < 4; ++mt) {
#pragma unroll
    for (int r = 0; r < 4; ++r) {
      const int gm = bm + wm + mt * 16 + quad * 4 + r;
      const float scv = sc[gm];
      const float c0v = c0f[gm];
      float sq = 0.f;
#pragma unroll
      for (int nt = 0; nt < 4; ++nt) {
        const int gn = bn + wn + nt * 16 + m16;
        float v = scv * (acc[mt][nt][r] - c0v * wc0[gn]) + bias[gn];
        Cb[(size_t)gm * N + gn] = f2bf(v);
        sq += (gn == 0) ? 0.f : v * v;
      }
      sq += __shfl_xor(sq, 1, 64);
      sq += __shfl_xor(sq, 2, 64);
      sq += __shfl_xor(sq, 4, 64);
      sq += __shfl_xor(sq, 8, 64);
      if (m16 == 0) part[(size_t)gm * NBLK + 2 * bxi + (wave & 1)] = sq;
    }
  }
}

// ---------------- 256x256 NT GEMM, lean 4x-unrolled pipeline ----------------
// 512 threads = 8 waves (2M x 4N); per-wave 128x64 output, acc[8][4].
// LDS: 4-slot ring of (A 256x32 + B 256x32) bf16 = 4 x 32KB = 128KB.
// R6 theory: VALUBusy 23% (533 cyc/iter/CU) from per-iter addr recompute,
//   runtime-slot ds adds, tail-clamp selects, and AGPR<->VGPR moves under
//   register pressure; VALU occupies the in-order issue slot and starves
//   MFMA issue at 2 waves/SIMD. Fix: unroll x4 (compile-time slots),
//   ds_read = precomputed byte-base + compile-time immediate (A/B x lo/hi
//   64KB bases since offset: is 16-bit), GLL ptrs advanced once per 4 tiles,
//   stage-free peeled tail (no clamp select), drop A-side reg double-buffer,
//   keep B-side one-tile-ahead pre-read (16 VGPR).
// vmcnt ledger (unchanged from R5): body b ends vmcnt(4) -> newest 4 = its own
//   stage (tile t+b+3); stages <= tile t+b+2 landed; barrier makes it
//   block-wide; body b+1 pre-reads b(t+b+2) = exactly resident. Prologue:
//   12 loads, vmcnt(4) -> tiles 0,1 resident. Tail (tiles NT-4..NT-1, slots
//   0..3): stage tile NT-1 (slot 3; WAR ok: slot-3 reads of tile NT-5 were
//   consumed before the last main barrier), TB0, then vmcnt(0)+barrier (tile
//   NT-2's stage was still in flight at loop exit; also covers tile NT-1
//   before TB3 and makes residency block-wide), TB1..TB3, no further sync.
// Frag m (0..7) of A at aoff + m*512 elems (unified: a2 region = +2048 = 4*512).
// Granule swizzle (measured 0 conflicts): LDS granule g of row r = global g ^ ((r>>1)&3).
// Epilogue: y = sc[m]*(acc - c0f[m]*wc0[n]) + bias[n]; partials part[gm*64 + bxi*4 + wc].
template<int N, int K>
__global__ __launch_bounds__(512, 2) void k_gemm256(
    const unsigned short* __restrict__ A,
    const unsigned short* __restrict__ B,
    const float* __restrict__ bias,
    const float* __restrict__ sc,
    const float* __restrict__ c0f,
    const float* __restrict__ wc0,
    unsigned short* __restrict__ Cb,
    float* __restrict__ part)
{
  static_assert(K % 128 == 0 && K / 32 >= 8, "need NT multiple of 4, >= 8");
  constexpr int NT = K / 32;
  __shared__ __align__(16) unsigned short S[4][2][8192];   // [slot][A/B][256*32]

  const int tid  = threadIdx.x;
  const int wave = tid >> 6;
  const int lane = tid & 63;
  const int quad = lane >> 4;
  const int m16  = lane & 15;
  const int wr   = wave >> 2;     // 0..1 (M)
  const int wc   = wave & 3;      // 0..3 (N)

  // bijective XCD swizzle: 512 blocks = 8 XCDs x 64; each XCD gets an 8x8 tile patch
  const int j = blockIdx.x & 7;
  const int k = blockIdx.x >> 3;                 // 0..63
  const int bxi = 8 * (j & 1) + (k & 7);         // 0..15  (N/256)
  const int byi = 8 * (j >> 1) + (k >> 3);       // 0..31  (M/256)
  const int bm = byi * 256;
  const int bn = bxi * 256;

  // staging: thread -> row tid>>2, LDS granule tid&3; global granule pre-swizzled
  const int gsw8 = (((tid & 3) ^ ((tid >> 3) & 3)) << 3);
  const unsigned short* gAp = A + (size_t)(bm + (tid >> 2)) * K + gsw8;
  const unsigned short* gAq = gAp + (size_t)128 * K;
  const unsigned short* gBp = B + (size_t)(bn + (tid >> 2)) * K + gsw8;
  const unsigned short* gBq = gBp + (size_t)128 * K;
  const int ldw = wave * 1024;         // byte offset of this wave's 16-row stripe

  // read-side swizzle + byte-base pointers (compile-time immediates per slot/frag)
  const int rsw8 = ((quad ^ ((m16 >> 1) & 3)) << 3);
  const int aoffB = ((wr * 128 + m16) * 32 + rsw8) * 2;
  const int boffB = ((wc * 64  + m16) * 32 + rsw8) * 2;
  const char* Sb  = (const char*)&S[0][0][0];
  const char* pA  = Sb + aoffB;                  // A slots 0,1
  const char* pA2 = pA + 65536;                  // A slots 2,3
  const char* pB  = Sb + 16384 + boffB;          // B slots 0,1
  const char* pB2 = pB + 65536;                  // B slots 2,3

  floatx4 acc[8][4];
#pragma unroll
  for (int i = 0; i < 8; ++i)
#pragma unroll
    for (int jj = 0; jj < 4; ++jj)
#pragma unroll
      for (int r = 0; r < 4; ++r) acc[i][jj][r] = 0.0f;

#define GLL(SRC, DST) __builtin_amdgcn_global_load_lds((gbl_void_t*)(void*)(SRC), (lds_void_t*)(DST), 16, 0, 0)
#define ARD(S_, M_) (*(const bf16x8*)(((S_) < 2 ? pA : pA2) + ((S_) * 32768 + (M_) * 1024 - ((S_) < 2 ? 0 : 65536))))
#define BRD(S_, N_) (*(const bf16x8*)(((S_) < 2 ? pB : pB2) + ((S_) * 32768 + (N_) * 1024 - ((S_) < 2 ? 0 : 65536))))
#define STG(T_, OFF) { \
    GLL(gAp + (OFF), (char*)Sb + (T_) * 32768 +         ldw); \
    GLL(gAq + (OFF), (char*)Sb + (T_) * 32768 +  8192 + ldw); \
    GLL(gBp + (OFF), (char*)Sb + (T_) * 32768 + 16384 + ldw); \
    GLL(gBq + (OFF), (char*)Sb + (T_) * 32768 + 24576 + ldw); }

  // prologue: stage tiles 0,1,2; vmcnt(4) -> tiles 0,1 resident
  STG(0, 0) STG(1, 32) STG(2, 64)
  asm volatile("s_waitcnt vmcnt(4)" ::: "memory");
  __builtin_amdgcn_s_barrier();

  bf16x8 bX[4], bY[4];
#pragma unroll
  for (int n = 0; n < 4; ++n) bX[n] = BRD(0, n);   // pre-read b(0)

  // main body BI (0..3): compute tile t+BI from slot BI, stage tile t+BI+3,
  // pre-read b(t+BI+1) between MFMA phases. BC = consume set, BN = preload set.
#define MBODY(BI, BC, BN)                                                              \
  {                                                                                    \
    STG((BI + 3) & 3, (BI + 3) * 32)                                                   \
    bf16x8 a_[8];                                                                      \
    _Pragma("unroll")                                                                  \
    for (int m = 0; m < 8; ++m) a_[m] = ARD(BI, m);                                    \
    __builtin_amdgcn_s_setprio(1);                                                     \
    _Pragma("unroll")                                                                  \
    for (int f = 0; f < 4; ++f)                                                        \
      _Pragma("unroll")                                                                \
      for (int n = 0; n < 4; ++n)                                                      \
        acc[f][n] = __builtin_amdgcn_mfma_f32_16x16x32_bf16(a_[f], BC[n], acc[f][n], 0, 0, 0); \
    __builtin_amdgcn_s_setprio(0);                                                     \
    _Pragma("unroll")                                                                  \
    for (int n = 0; n < 4; ++n) BN[n] = BRD((BI + 1) & 3, n);                          \
    __builtin_amdgcn_s_setprio(1);                                                     \
    _Pragma("unroll")                                                                  \
    for (int f = 0; f < 4; ++f)                                                        \
      _Pragma("unroll")                                                                \
      for (int n = 0; n < 4; ++n)                                                      \
        acc[f + 4][n] = __builtin_amdgcn_mfma_f32_16x16x32_bf16(a_[f + 4], BC[n], acc[f + 4][n], 0, 0, 0); \
    __builtin_amdgcn_s_setprio(0);                                                     \
    asm volatile("s_waitcnt vmcnt(4)" ::: "memory");                                   \
    __builtin_amdgcn_s_barrier();                                                      \
  }

  // tail body: no staging, no sync; BC consumed; optionally preload BN
#define TBODY(BI, BC)                                                                  \
  {                                                                                    \
    bf16x8 a_[8];                                                                      \
    _Pragma("unroll")                                                                  \
    for (int m = 0; m < 8; ++m) a_[m] = ARD(BI, m);                                    \
    __builtin_amdgcn_s_setprio(1);                                                     \
    _Pragma("unroll")                                                                  \
    for (int f = 0; f < 4; ++f)                                                        \
      _Pragma("unroll")                                                                \
      for (int n = 0; n < 4; ++n)                                                      \
        acc[f][n] = __builtin_amdgcn_mfma_f32_16x16x32_bf16(a_[f], BC[n], acc[f][n], 0, 0, 0); \
    _Pragma("unroll")                                                                  \
    for (int f = 0; f < 4; ++f)                                                        \
      _Pragma("unroll")                                                                \
      for (int n = 0; n < 4; ++n)                                                      \
        acc[f + 4][n] = __builtin_amdgcn_mfma_f32_16x16x32_bf16(a_[f + 4], BC[n], acc[f + 4][n], 0, 0, 0); \
    __builtin_amdgcn_s_setprio(0);                                                     \
  }

  for (int t = 0; t < NT - 4; t += 4) {
    MBODY(0, bX, bY)
    MBODY(1, bY, bX)
    MBODY(2, bX, bY)
    MBODY(3, bY, bX)
    gAp += 128; gAq += 128; gBp += 128; gBq += 128;
  }

  // tail: tiles NT-4..NT-1 in slots 0..3. Stage tile NT-1 (slot 3; col offset 96).
  STG(3, 96)
  // TB0 (tile NT-4, slot 0): consume bX (pre-read by last main body), preload bY=b(NT-3)
  {
    bf16x8 a_[8];
#pragma unroll
    for (int m = 0; m < 8; ++m) a_[m] = ARD(0, m);
    __builtin_amdgcn_s_setprio(1);
#pragma unroll
    for (int f = 0; f < 4; ++f)
#pragma unroll
      for (int n = 0; n < 4; ++n)
        acc[f][n] = __builtin_amdgcn_mfma_f32_16x16x32_bf16(a_[f], bX[n], acc[f][n], 0, 0, 0);
    __builtin_amdgcn_s_setprio(0);
#pragma unroll
    for (int n = 0; n < 4; ++n) bY[n] = BRD(1, n);
    __builtin_amdgcn_s_setprio(1);
#pragma unroll
    for (int f = 0; f < 4; ++f)
#pragma unroll
      for (int n = 0; n < 4; ++n)
        acc[f + 4][n] = __builtin_amdgcn_mfma_f32_16x16x32_bf16(a_[f + 4], bX[n], acc[f + 4][n], 0, 0, 0);
    __builtin_amdgcn_s_setprio(0);
  }
  // all remaining tiles (NT-2 stage was in flight at loop exit; NT-1 staged above):
  asm volatile("s_waitcnt vmcnt(0)" ::: "memory");
  __builtin_amdgcn_s_barrier();
  // TB1 (tile NT-3, slot 1): consume bY, preload bX=b(NT-2)
  {
    bf16x8 a_[8];
#pragma unroll
    for (int m = 0; m < 8; ++m) a_[m] = ARD(1, m);
    __builtin_amdgcn_s_setprio(1);
#pragma unroll
    for (int f = 0; f < 4; ++f)
#pragma unroll
      for (int n = 0; n < 4; ++n)
        acc[f][n] = __builtin_amdgcn_mfma_f32_16x16x32_bf16(a_[f], bY[n], acc[f][n], 0, 0, 0);
    __builtin_amdgcn_s_setprio(0);
#pragma unroll
    for (int n = 0; n < 4; ++n) bX[n] = BRD(2, n);
    __builtin_amdgcn_s_setprio(1);
#pragma unroll
    for (int f = 0; f < 4; ++f)
#pragma unroll
      for (int n = 0; n < 4; ++n)
        acc[f + 4][n] = __builtin_amdgcn_mfma_f32_16x16x32_bf16(a_[f + 4], bY[n], acc[f + 4][n], 0, 0, 0);
    __builtin_amdgcn_s_setprio(0);
  }
  // TB2 (tile NT-2, slot 2): consume bX, preload bY=b(NT-1)
  {
    bf16x8 a_[8];
#pragma unroll
    for (int m = 0; m < 8; ++m) a_[m] = ARD(2, m);
    __builtin_amdgcn_s_setprio(1);
#pragma unroll
    for (int f = 0; f < 4; ++f)
#pragma unroll
      for (int n = 0; n < 4; ++n)
        acc[f][n] = __builtin_amdgcn_mfma_f32_16x16x32_bf16(a_[f], bX[n], acc[f][n], 0, 0, 0);
    __builtin_amdgcn_s_setprio(0);
#pragma unroll
    for (int n = 0; n < 4; ++n) bY[n] = BRD(3, n);
    __builtin_amdgcn_s_setprio(1);
#pragma unroll
    for (int f = 0; f < 4; ++f)
#pragma unroll
      for (int n = 0; n < 4; ++n)
        acc[f + 4][n] = __builtin_amdgcn_mfma_f32_16x16x32_bf16(a_[f + 4], bX[n], acc[f + 4][n], 0, 0, 0);
    __builtin_amdgcn_s_setprio(0);
  }
  // TB3 (tile NT-1, slot 3): consume bY
  TBODY(3, bY)

#undef TBODY
#undef MBODY
#undef STG
#undef BRD
#undef ARD
#undef GLL

  // epilogue: C/D layout col = lane&15, row = quad*4 + r
  const int wm = wr * 128;
  const int wn = wc * 64;
#pragma unroll
  for (int mt = 0; mt < 8; ++mt) {
#pragma unroll
    for (int r = 0; r < 4; ++r) {
      const int gm = bm + wm + mt * 16 + quad * 4 + r;
      const float scv = sc[gm];
      const float c0v = c0f[gm];
      float sq = 0.f;
#pragma unroll
      for (int nt = 0; nt < 4; ++nt) {
        const int gn = bn + wn + nt * 16 + m16;
        float v = scv * (acc[mt][nt][r] - c0v * wc0[gn]) + bias[gn];
        Cb[(size_t)gm * N + gn] = f2bf(v);
        sq += (gn == 0) ? 0.f : v * v;
      }
      sq += __shfl_xor(sq, 1, 64);
      sq += __shfl_xor(sq, 2, 64);
      sq += __shfl_xor(sq, 4, 64);
      sq += __shfl_xor(sq, 8, 64);
      if (m16 == 0) part[(size_t)gm * 64 + bxi * 4 + wc] = sq;
    }
  }
}

extern "C" void kernel_launch(void* const* d_in, const int* in_sizes, int n_in,
                              void* d_out, int out_size, void* d_ws, size_t ws_size,
                              hipStream_t stream) {
  const void* x  = d_in[0];
  const void* W1 = d_in[1];
  const void* b1 = d_in[2];
  const void* W2 = d_in[3];
  const void* b2 = d_in[4];
  const void* W3 = d_in[5];
  const void* b3 = d_in[6];

  const int NR = 8192, DIN = 1024, DH = 4096, DOUT = 1024;

  char* ws = (char*)d_ws;
  size_t off = 0;
  int* mode = (int*)(ws + off);                        off += 256;
  unsigned short* W1b = (unsigned short*)(ws + off);   off += (size_t)DH * DIN * 2;
  unsigned short* W2b = (unsigned short*)(ws + off);   off += (size_t)DH * DH * 2;
  unsigned short* W3b = (unsigned short*)(ws + off);   off += (size_t)DOUT * DH * 2;
  unsigned short* xb  = (unsigned short*)(ws + off);   off += (size_t)NR * DIN * 2;
  unsigned short* y1  = (unsigned short*)(ws + off);   off += (size_t)NR * DH * 2;
  unsigned short* y2  = (unsigned short*)(ws + off);   off += (size_t)NR * DH * 2;
  unsigned short* y3  = (unsigned short*)(ws + off);   off += (size_t)NR * DOUT * 2;
  float* part1 = (float*)(ws + off);                   off += (size_t)NR * 64 * 4;
  float* part2 = (float*)(ws + off);                   off += (size_t)NR * 64 * 4;
  float* part3 = (float*)(ws + off);                   off += (size_t)NR * 16 * 4;
  float* sc0  = (float*)(ws + off);                    off += (size_t)NR * 4;
  float* x0c  = (float*)(ws + off);                    off += (size_t)NR * 4;
  float* sc1  = (float*)(ws + off);                    off += (size_t)NR * 4;
  float* c01  = (float*)(ws + off);                    off += (size_t)NR * 4;
  float* sc2  = (float*)(ws + off);                    off += (size_t)NR * 4;
  float* c02  = (float*)(ws + off);                    off += (size_t)NR * 4;
  float* ss3  = (float*)(ws + off);                    off += (size_t)NR * 4;
  float* w1c0 = (float*)(ws + off);                    off += (size_t)DH * 4;
  float* w2c0 = (float*)(ws + off);                    off += (size_t)DH * 4;
  float* w3c0 = (float*)(ws + off);                    off += (size_t)DOUT * 4;
  float* b1f  = (float*)(ws + off);                    off += (size_t)DH * 4;
  float* b2f  = (float*)(ws + off);                    off += (size_t)DH * 4;
  float* b3f  = (float*)(ws + off);                    off += (size_t)DOUT * 4;

  k_init<<<16, 256, 0, stream>>>((const unsigned short*)x, mode, b1, b2, b3, b1f, b2f, b3f);

  k_cvtw<128><<<(DH * DIN / 8 + 255) / 256, 256, 0, stream>>>(W1, W1b, mode, DH * DIN / 8, w1c0);
  k_cvtw<512><<<(DH * DH  / 8 + 255) / 256, 256, 0, stream>>>(W2, W2b, mode, DH * DH / 8, w2c0);
  k_cvtw<512><<<(DOUT * DH / 8 + 255) / 256, 256, 0, stream>>>(W3, W3b, mode, DOUT * DH / 8, w3c0);

  k_prep<<<NR, 256, 0, stream>>>(x, xb, sc0, x0c, mode);

  k_gemm256<4096, 1024><<<512, 512, 0, stream>>>(
      xb, W1b, b1f, sc0, x0c, w1c0, y1, part1);
  k_sc<64><<<(NR + 255) / 256, 256, 0, stream>>>(part1, y1, DH, sc1, c01, nullptr, NR);

  k_gemm256<4096, 4096><<<512, 512, 0, stream>>>(
      y1, W2b, b2f, sc1, c01, w2c0, y2, part2);
  k_sc<64><<<(NR + 255) / 256, 256, 0, stream>>>(part2, y2, DH, sc2, c02, nullptr, NR);

  k_gemm_bt<1024, 4096, 16, 8><<<512, 256, 0, stream>>>(
      y2, W3b, b3f, sc2, c02, w3c0, y3, part3);
  k_sc<16><<<(NR + 255) / 256, 256, 0, stream>>>(part3, y3, DOUT, sc0, x0c, ss3, NR);

  k_final<<<NR, 256, 0, stream>>>(y3, ss3, d_out, mode);
}